// Round 1
// baseline (136.676 us; speedup 1.0000x reference)
//
#include <hip/hip_runtime.h>
#include <math.h>

// Problem constants (fixed by reference):
// x: (512, 3, 32, 32) fp32
// layer1: C=3 -> F=32, R=16, 3x3  -> (512,32,30,30)
// layer2: C=32 -> F=32, R=16, 3x3 -> (512,32,28,28)
// classifier: 25088 -> 10, then log_softmax
//
// Algebraic fusion:
//   M[r1][r2]      = sum_f l1_f0[f][r1] * l2_f3[f][r2]            (16x16)
//   Wc2[n][r2][q]  = sum_f l2_f0[f][r2] * W_cls[n][f*784+q]       (10x16x784)
// so h1 and h2 are never materialized.

#define NTHREADS 512

__global__ void precomp_kernel(const float* __restrict__ l1_f0,
                               const float* __restrict__ l2_f0,
                               const float* __restrict__ l2_f3,
                               const float* __restrict__ Wcls,
                               float* __restrict__ Wc2,
                               float* __restrict__ Mm) {
    int id = blockIdx.x * blockDim.x + threadIdx.x;
    if (id < 10 * 16 * 784) {
        int n = id / (16 * 784);
        int rem = id - n * (16 * 784);
        int r2 = rem / 784;
        int pix = rem - r2 * 784;
        float acc = 0.f;
#pragma unroll
        for (int f = 0; f < 32; ++f)
            acc += l2_f0[f * 16 + r2] * Wcls[n * 25088 + f * 784 + pix];
        Wc2[id] = acc;
    }
    if (id < 256) {
        int r1 = id >> 4, r2 = id & 15;
        float acc = 0.f;
#pragma unroll
        for (int f = 0; f < 32; ++f)
            acc += l1_f0[f * 16 + r1] * l2_f3[f * 16 + r2];
        Mm[id] = acc;
    }
}

__global__ __launch_bounds__(NTHREADS) void fused_kernel(
    const float* __restrict__ x,
    const float* __restrict__ l1_f1, const float* __restrict__ l1_f2,
    const float* __restrict__ l1_f3,
    const float* __restrict__ l2_f1, const float* __restrict__ l2_f2,
    const float* __restrict__ Wc2, const float* __restrict__ Mm,
    const float* __restrict__ b_cls,
    float* __restrict__ out) {
    // Big ping-pong buffers: sA holds s1 (16x1024) then u (16x900);
    // sB holds t1 (16x900) then t2 (16x784).
    __shared__ float sA[16 * 1024];   // 64 KB
    __shared__ float sB[16 * 900];    // 57.6 KB
    __shared__ float sw1[144];        // per-rank 3x3 weights, layer 1
    __shared__ float sw2[144];        // per-rank 3x3 weights, layer 2
    __shared__ float sf3[48];         // l1_f3 (3x16)
    __shared__ float sM[256];         // M (16x16)
    __shared__ float sred[8 * 10];    // per-wave logit partials
    __shared__ float slog[10];

    const int tid = threadIdx.x;
    const int b = blockIdx.x;

    // ---- stage 0: small weights into LDS ----
    if (tid < 48) sf3[tid] = l1_f3[tid];
    if (tid < 144) {
        int r = tid / 9, ij = tid - r * 9;
        int i = ij / 3, j = ij - i * 3;
        sw1[tid] = l1_f1[i * 16 + r] * l1_f2[j * 16 + r];
    }
    if (tid >= 144 && tid < 288) {
        int t = tid - 144;
        int r = t / 9, ij = t - r * 9;
        int i = ij / 3, j = ij - i * 3;
        sw2[t] = l2_f1[i * 16 + r] * l2_f2[j * 16 + r];
    }
    if (tid < 256) sM[tid] = Mm[tid];
    __syncthreads();

    // ---- stage 1: s1[r][p] = sum_c x[b][c][p] * l1_f3[c][r] ----
    for (int p = tid; p < 1024; p += NTHREADS) {
        float x0 = x[b * 3072 + p];
        float x1 = x[b * 3072 + 1024 + p];
        float x2 = x[b * 3072 + 2048 + p];
#pragma unroll
        for (int r = 0; r < 16; ++r)
            sA[r * 1024 + p] = x0 * sf3[r] + x1 * sf3[16 + r] + x2 * sf3[32 + r];
    }
    __syncthreads();

    // ---- stage 2: t1[r][ho][wo] = 3x3 conv of s1[r] with w1[r] ----
    for (int idx = tid; idx < 16 * 900; idx += NTHREADS) {
        int r = idx / 900;
        int q = idx - r * 900;
        int ho = q / 30;
        int wo = q - ho * 30;
        const float* sp = &sA[r * 1024 + ho * 32 + wo];
        const float* wp = &sw1[r * 9];
        float acc = 0.f;
#pragma unroll
        for (int i = 0; i < 3; ++i)
#pragma unroll
            for (int j = 0; j < 3; ++j)
                acc += wp[i * 3 + j] * sp[i * 32 + j];
        sB[idx] = acc;
    }
    __syncthreads();

    // ---- stage 3: u[r2][p] = sum_r1 t1[r1][p] * M[r1][r2] (into sA) ----
    for (int idx = tid; idx < 16 * 900; idx += NTHREADS) {
        int r2 = idx / 900;
        int p = idx - r2 * 900;
        float acc = 0.f;
#pragma unroll
        for (int r1 = 0; r1 < 16; ++r1)
            acc += sB[r1 * 900 + p] * sM[r1 * 16 + r2];
        sA[r2 * 900 + p] = acc;
    }
    __syncthreads();

    // ---- stage 4: t2[r2][ho][wo] = 3x3 conv of u[r2] with w2[r2] (into sB) ----
    for (int idx = tid; idx < 16 * 784; idx += NTHREADS) {
        int r2 = idx / 784;
        int q = idx - r2 * 784;
        int ho = q / 28;
        int wo = q - ho * 28;
        const float* sp = &sA[r2 * 900 + ho * 30 + wo];
        const float* wp = &sw2[r2 * 9];
        float acc = 0.f;
#pragma unroll
        for (int i = 0; i < 3; ++i)
#pragma unroll
            for (int j = 0; j < 3; ++j)
                acc += wp[i * 3 + j] * sp[i * 30 + j];
        sB[idx] = acc;
    }
    __syncthreads();

    // ---- stage 5: logits[n] = b[n] + sum_e t2[e] * Wc2[n][e] ----
    float acc[10];
#pragma unroll
    for (int n = 0; n < 10; ++n) acc[n] = 0.f;
    for (int e = tid; e < 12544; e += NTHREADS) {
        float tv = sB[e];
#pragma unroll
        for (int n = 0; n < 10; ++n)
            acc[n] += tv * Wc2[n * 12544 + e];
    }
    // wave (64-lane) shuffle reduce, then cross-wave via LDS
#pragma unroll
    for (int n = 0; n < 10; ++n) {
        float v = acc[n];
        for (int off = 32; off > 0; off >>= 1)
            v += __shfl_down(v, off, 64);
        if ((tid & 63) == 0) sred[(tid >> 6) * 10 + n] = v;
    }
    __syncthreads();
    if (tid < 10) {
        float lg = b_cls[tid];
#pragma unroll
        for (int w = 0; w < 8; ++w) lg += sred[w * 10 + tid];
        slog[tid] = lg;
    }
    __syncthreads();
    if (tid < 10) {
        float m = -1e30f;
#pragma unroll
        for (int n = 0; n < 10; ++n) m = fmaxf(m, slog[n]);
        float s = 0.f;
#pragma unroll
        for (int n = 0; n < 10; ++n) s += expf(slog[n] - m);
        out[b * 10 + tid] = slog[tid] - m - logf(s);
    }
}

extern "C" void kernel_launch(void* const* d_in, const int* in_sizes, int n_in,
                              void* d_out, int out_size, void* d_ws, size_t ws_size,
                              hipStream_t stream) {
    const float* x     = (const float*)d_in[0];
    const float* l1_f0 = (const float*)d_in[1];
    const float* l1_f1 = (const float*)d_in[2];
    const float* l1_f2 = (const float*)d_in[3];
    const float* l1_f3 = (const float*)d_in[4];
    const float* l2_f0 = (const float*)d_in[5];
    const float* l2_f1 = (const float*)d_in[6];
    const float* l2_f2 = (const float*)d_in[7];
    const float* l2_f3 = (const float*)d_in[8];
    const float* Wcls  = (const float*)d_in[9];
    const float* bcls  = (const float*)d_in[10];
    float* out = (float*)d_out;

    // ws layout: Wc2 [10*16*784] floats, then M [256] floats (~503 KB total)
    float* Wc2 = (float*)d_ws;
    float* Mm  = Wc2 + 10 * 16 * 784;

    precomp_kernel<<<dim3((10 * 16 * 784 + 255) / 256), dim3(256), 0, stream>>>(
        l1_f0, l2_f0, l2_f3, Wcls, Wc2, Mm);
    fused_kernel<<<dim3(512), dim3(NTHREADS), 0, stream>>>(
        x, l1_f1, l1_f2, l1_f3, l2_f1, l2_f2, Wc2, Mm, bcls, out);
}

// Round 2
// 104.796 us; speedup vs baseline: 1.3042x; 1.3042x over previous
//
#include <hip/hip_runtime.h>
#include <math.h>

// x: (512, 3, 32, 32) fp32
// layer1: C=3 -> F=32, R=16, 3x3  -> (512,32,30,30)
// layer2: C=32 -> F=32, R=16, 3x3 -> (512,32,28,28)
// classifier: 25088 -> 10, then log_softmax
//
// Algebraic fusion (h1, h2 never materialized):
//   M[r1][r2]      = sum_f l1_f0[f][r1] * l2_f3[f][r2]            (16x16)
//   Wc2[n][r2][q]  = sum_f l2_f0[f][r2] * W_cls[n][f*784+q]       (10x16x784)

#define NT 1024

__global__ void precomp_kernel(const float* __restrict__ l1_f0,
                               const float* __restrict__ l2_f0,
                               const float* __restrict__ l2_f3,
                               const float* __restrict__ Wcls,
                               float* __restrict__ Wc2,
                               float* __restrict__ Mm) {
    int id = blockIdx.x * blockDim.x + threadIdx.x;
    if (id < 10 * 16 * 784) {
        int n = id / (16 * 784);
        int rem = id - n * (16 * 784);
        int r2 = rem / 784;
        int pix = rem - r2 * 784;
        float acc = 0.f;
#pragma unroll
        for (int f = 0; f < 32; ++f)
            acc += l2_f0[f * 16 + r2] * Wcls[n * 25088 + f * 784 + pix];
        Wc2[id] = acc;
    }
    if (id < 256) {
        int r1 = id >> 4, r2 = id & 15;
        float acc = 0.f;
#pragma unroll
        for (int f = 0; f < 32; ++f)
            acc += l1_f0[f * 16 + r1] * l2_f3[f * 16 + r2];
        Mm[id] = acc;
    }
}

__global__ __launch_bounds__(NT) void fused_kernel(
    const float* __restrict__ x,
    const float* __restrict__ l1_f1, const float* __restrict__ l1_f2,
    const float* __restrict__ l1_f3,
    const float* __restrict__ l2_f1, const float* __restrict__ l2_f2,
    const float* __restrict__ Wc2, const float* __restrict__ Mm,
    const float* __restrict__ b_cls,
    float* __restrict__ out) {
    // sA: s1 (16x1024) then u (16x900). sB: t1 (16x900) then t2 (16x784).
    __shared__ float sA[16 * 1024];   // 64 KB
    __shared__ float sB[16 * 900];    // 57.6 KB
    __shared__ float sw1[144];
    __shared__ float sw2[144];
    __shared__ float sf3[48];
    __shared__ float sM[256];         // M (16x16), row-major [r1][r2]
    __shared__ float sred[16 * 10];
    __shared__ float slog[10];

    const int tid = threadIdx.x;
    const int b = blockIdx.x;

    // ---- stage 0: small weights into LDS ----
    if (tid < 48) sf3[tid] = l1_f3[tid];
    if (tid < 144) {
        int r = tid / 9, ij = tid - r * 9;
        int i = ij / 3, j = ij - i * 3;
        sw1[tid] = l1_f1[i * 16 + r] * l1_f2[j * 16 + r];
    }
    if (tid >= 144 && tid < 288) {
        int t = tid - 144;
        int r = t / 9, ij = t - r * 9;
        int i = ij / 3, j = ij - i * 3;
        sw2[t] = l2_f1[i * 16 + r] * l2_f2[j * 16 + r];
    }
    if (tid >= 288 && tid < 544) sM[tid - 288] = Mm[tid - 288];
    __syncthreads();

    // ---- stage 1: s1[r][p] = sum_c x[b][c][p] * l1_f3[c][r]; p = tid ----
    {
        const int p = tid;  // 1024 pixels, 1024 threads
        float x0 = x[b * 3072 + p];
        float x1 = x[b * 3072 + 1024 + p];
        float x2 = x[b * 3072 + 2048 + p];
#pragma unroll
        for (int r = 0; r < 16; ++r)
            sA[r * 1024 + p] = x0 * sf3[r] + x1 * sf3[16 + r] + x2 * sf3[32 + r];
    }
    __syncthreads();

    // ---- stage 2: t1[r] = conv3x3(s1[r], w1[r]) -> sB[r*900 + ho*30 + wo]
    // thread -> (r = tid>>6, col = tid&31, half = (tid>>5)&1); sliding window down column
    {
        const int r = tid >> 6;
        const int s = tid & 63;
        const int col = s & 31;
        const int half = s >> 5;
        if (col < 30) {
            const float* wp = &sw1[r * 9];
            float w0 = wp[0], w1 = wp[1], w2 = wp[2];
            float w3 = wp[3], w4 = wp[4], w5 = wp[5];
            float w6 = wp[6], w7 = wp[7], w8 = wp[8];
            const int ho0 = half * 15;
            const float* base = &sA[r * 1024 + ho0 * 32 + col];
            float a0 = base[0],  a1 = base[1],  a2 = base[2];
            float b0 = base[32], b1 = base[33], b2 = base[34];
            float* op = &sB[r * 900 + ho0 * 30 + col];
#pragma unroll
            for (int step = 0; step < 15; ++step) {
                const float* rp = base + (step + 2) * 32;
                float c0 = rp[0], c1 = rp[1], c2 = rp[2];
                float acc = w0 * a0 + w1 * a1 + w2 * a2
                          + w3 * b0 + w4 * b1 + w5 * b2
                          + w6 * c0 + w7 * c1 + w8 * c2;
                op[step * 30] = acc;
                a0 = b0; a1 = b1; a2 = b2;
                b0 = c0; b1 = c1; b2 = c2;
            }
        }
    }
    __syncthreads();

    // ---- stage 3: u[r2][p] = sum_r1 t1[r1][p] * M[r1][r2] -> sA
    // thread tile: 4 pixels x 4 r2 (900 tiles, float4 LDS reads)
    {
        if (tid < 900) {
            const int tile_r = tid & 3;
            const int tile_p = tid >> 2;      // 0..224
            const int r2b = tile_r * 4;
            const int p4 = tile_p * 4;
            float acc0x = 0.f, acc0y = 0.f, acc0z = 0.f, acc0w = 0.f;
            float acc1x = 0.f, acc1y = 0.f, acc1z = 0.f, acc1w = 0.f;
            float acc2x = 0.f, acc2y = 0.f, acc2z = 0.f, acc2w = 0.f;
            float acc3x = 0.f, acc3y = 0.f, acc3z = 0.f, acc3w = 0.f;
#pragma unroll
            for (int r1 = 0; r1 < 16; ++r1) {
                float4 tv = *(const float4*)&sB[r1 * 900 + p4];
                float4 mv = *(const float4*)&sM[r1 * 16 + r2b];
                acc0x += mv.x * tv.x; acc0y += mv.x * tv.y; acc0z += mv.x * tv.z; acc0w += mv.x * tv.w;
                acc1x += mv.y * tv.x; acc1y += mv.y * tv.y; acc1z += mv.y * tv.z; acc1w += mv.y * tv.w;
                acc2x += mv.z * tv.x; acc2y += mv.z * tv.y; acc2z += mv.z * tv.z; acc2w += mv.z * tv.w;
                acc3x += mv.w * tv.x; acc3y += mv.w * tv.y; acc3z += mv.w * tv.z; acc3w += mv.w * tv.w;
            }
            *(float4*)&sA[(r2b + 0) * 900 + p4] = make_float4(acc0x, acc0y, acc0z, acc0w);
            *(float4*)&sA[(r2b + 1) * 900 + p4] = make_float4(acc1x, acc1y, acc1z, acc1w);
            *(float4*)&sA[(r2b + 2) * 900 + p4] = make_float4(acc2x, acc2y, acc2z, acc2w);
            *(float4*)&sA[(r2b + 3) * 900 + p4] = make_float4(acc3x, acc3y, acc3z, acc3w);
        }
    }
    __syncthreads();

    // ---- stage 4: t2[r2] = conv3x3(u[r2], w2[r2]) -> sB[r2*784 + ho*28 + wo]
    {
        const int r2 = tid >> 6;
        const int s = tid & 63;
        const int col = s & 31;
        const int half = s >> 5;
        if (col < 28) {
            const float* wp = &sw2[r2 * 9];
            float w0 = wp[0], w1 = wp[1], w2 = wp[2];
            float w3 = wp[3], w4 = wp[4], w5 = wp[5];
            float w6 = wp[6], w7 = wp[7], w8 = wp[8];
            const int ho0 = half * 14;
            const float* base = &sA[r2 * 900 + ho0 * 30 + col];
            float a0 = base[0],  a1 = base[1],  a2 = base[2];
            float b0 = base[30], b1 = base[31], b2 = base[32];
            float* op = &sB[r2 * 784 + ho0 * 28 + col];
#pragma unroll
            for (int step = 0; step < 14; ++step) {
                const float* rp = base + (step + 2) * 30;
                float c0 = rp[0], c1 = rp[1], c2 = rp[2];
                float acc = w0 * a0 + w1 * a1 + w2 * a2
                          + w3 * b0 + w4 * b1 + w5 * b2
                          + w6 * c0 + w7 * c1 + w8 * c2;
                op[step * 28] = acc;
                a0 = b0; a1 = b1; a2 = b2;
                b0 = c0; b1 = c1; b2 = c2;
            }
        }
    }
    __syncthreads();

    // ---- stage 5: logits[n] = b[n] + sum_e t2[e] * Wc2[n][e]; float4 over e ----
    float acc[10];
#pragma unroll
    for (int n = 0; n < 10; ++n) acc[n] = 0.f;
    for (int q = tid; q < 3136; q += NT) {
        float4 tv = *(const float4*)&sB[q * 4];
#pragma unroll
        for (int n = 0; n < 10; ++n) {
            float4 wv = *(const float4*)&Wc2[n * 12544 + q * 4];
            acc[n] += tv.x * wv.x + tv.y * wv.y + tv.z * wv.z + tv.w * wv.w;
        }
    }
#pragma unroll
    for (int n = 0; n < 10; ++n) {
        float v = acc[n];
        for (int off = 32; off > 0; off >>= 1)
            v += __shfl_down(v, off, 64);
        if ((tid & 63) == 0) sred[(tid >> 6) * 10 + n] = v;
    }
    __syncthreads();
    if (tid < 10) {
        float lg = b_cls[tid];
#pragma unroll
        for (int w = 0; w < 16; ++w) lg += sred[w * 10 + tid];
        slog[tid] = lg;
    }
    __syncthreads();
    if (tid < 10) {
        float m = -1e30f;
#pragma unroll
        for (int n = 0; n < 10; ++n) m = fmaxf(m, slog[n]);
        float s = 0.f;
#pragma unroll
        for (int n = 0; n < 10; ++n) s += expf(slog[n] - m);
        out[b * 10 + tid] = slog[tid] - m - logf(s);
    }
}

extern "C" void kernel_launch(void* const* d_in, const int* in_sizes, int n_in,
                              void* d_out, int out_size, void* d_ws, size_t ws_size,
                              hipStream_t stream) {
    const float* x     = (const float*)d_in[0];
    const float* l1_f0 = (const float*)d_in[1];
    const float* l1_f1 = (const float*)d_in[2];
    const float* l1_f2 = (const float*)d_in[3];
    const float* l1_f3 = (const float*)d_in[4];
    const float* l2_f0 = (const float*)d_in[5];
    const float* l2_f1 = (const float*)d_in[6];
    const float* l2_f2 = (const float*)d_in[7];
    const float* l2_f3 = (const float*)d_in[8];
    const float* Wcls  = (const float*)d_in[9];
    const float* bcls  = (const float*)d_in[10];
    float* out = (float*)d_out;

    float* Wc2 = (float*)d_ws;                 // 10*16*784 floats
    float* Mm  = Wc2 + 10 * 16 * 784;          // 256 floats

    precomp_kernel<<<dim3((10 * 16 * 784 + 255) / 256), dim3(256), 0, stream>>>(
        l1_f0, l2_f0, l2_f3, Wcls, Wc2, Mm);
    fused_kernel<<<dim3(512), dim3(NT), 0, stream>>>(
        x, l1_f1, l1_f2, l1_f3, l2_f1, l2_f2, Wc2, Mm, bcls, out);
}